// Round 1
// baseline (296.331 us; speedup 1.0000x reference)
//
#include <hip/hip_runtime.h>
#include <math.h>

// SSNet forward. Input order (setup_inputs):
// 0 x[2,1,256,256] f32, 1 ROI[2,5,1,4] i32, 2 roi_layer (scalar=3),
// 3..8  w1[3,1,5,5] b1 g1 be1 m1 v1
// 9..14 w2[20,1,5,5] b2 g2 be2 m2 v2
// 15..20 w3[50,35,5,5] b3 g3 be3 m3 v3
// 21..26 w4[25,50,5,5] b4 g4 be4 m4 v4
// 27 fw1[19600,1024] 28 fb1[1024] 29 fw2[1024,32] 30 fb2[32] 31 fw3[32,2] 32 fb3[2]
// Output: softmax [2,2] f32.
// roi_layer is fixed at 3 by setup_inputs; grid shapes depend on it -> hard-coded RL=3.

#define RL 3
#define NCH 35   // 20 + 5*RL

__device__ __forceinline__ float bn_apply(float x, float g, float be, float m, float v) {
    float inv = g * rsqrtf(v + 1e-5f);
    return x * inv + (be - m * inv);
}

// conv 5x5, 1 input channel, on 256x256 -> [B,C,252,252], + bias + BN + ReLU
__global__ void conv5_c1_bnrelu(const float* __restrict__ x, const float* __restrict__ w,
                                const float* __restrict__ b, const float* __restrict__ g,
                                const float* __restrict__ be, const float* __restrict__ m,
                                const float* __restrict__ v, float* __restrict__ out, int C) {
    int idx = blockIdx.x * blockDim.x + threadIdx.x;
    int total = 2 * C * 252 * 252;
    if (idx >= total) return;
    int ox = idx % 252;
    int t = idx / 252;
    int oy = t % 252; t /= 252;
    int c = t % C;
    int bi = t / C;
    const float* xp = x + bi * 256 * 256 + oy * 256 + ox;
    const float* wp = w + c * 25;
    float acc = 0.f;
#pragma unroll
    for (int ky = 0; ky < 5; ky++)
#pragma unroll
        for (int kx = 0; kx < 5; kx++)
            acc += xp[ky * 256 + kx] * wp[ky * 5 + kx];
    acc += b[c];
    acc = bn_apply(acc, g[c], be[c], m[c], v[c]);
    out[idx] = fmaxf(acc, 0.f);
}

// 4x4 stride-2 max pool of [2,20,252,252] -> channels 0..19 of h1 [2,35,125,125]
__global__ void pool4s2(const float* __restrict__ in, float* __restrict__ h1) {
    int idx = blockIdx.x * blockDim.x + threadIdx.x;
    int total = 2 * 20 * 125 * 125;
    if (idx >= total) return;
    int ox = idx % 125;
    int t = idx / 125;
    int oy = t % 125; t /= 125;
    int c = t % 20;
    int bi = t / 20;
    const float* ip = in + ((bi * 20 + c) * 252 + oy * 2) * 252 + ox * 2;
    float mx = -INFINITY;
#pragma unroll
    for (int ky = 0; ky < 4; ky++)
#pragma unroll
        for (int kx = 0; kx < 4; kx++)
            mx = fmaxf(mx, ip[ky * 252 + kx]);
    h1[((bi * NCH + c) * 125 + oy) * 125 + ox] = mx;
}

// ROI adaptive max pool: roiX[2,3,252,252] -> channels 20..34 of h1.
// Batch order REVERSED (crops[1] + crops[0]): out batch b reads source batch 1-b.
// coord scale: int(v*0.9) == (9*v)/10 for v>=0.
__global__ void roipool(const float* __restrict__ roiX, const int* __restrict__ ROI,
                        float* __restrict__ h1) {
    int idx = blockIdx.x * blockDim.x + threadIdx.x;
    int total = 2 * (5 * RL) * 125 * 125;
    if (idx >= total) return;
    int ox = idx % 125;
    int t = idx / 125;
    int oy = t % 125; t /= 125;
    int cc = t % (5 * RL);
    int bi = t / (5 * RL);
    int sb = 1 - bi;
    int j = cc / 5;   // channel of roiX
    int i = cc % 5;   // roi index
    const int* rp = ROI + (sb * 5 + i) * 4;  // (y1,y2,x1,x2)
    int y1 = (9 * rp[0]) / 10;
    int y2 = (9 * rp[1]) / 10;
    int x1 = (9 * rp[2]) / 10;
    int x2 = (9 * rp[3]) / 10;
    int H = y2 - y1;
    int W = x2 - x1;
    // PyTorch adaptive bins: s = floor(o*n/125), e = ceil((o+1)*n/125)
    int sy = (oy * H) / 125, ey = ((oy + 1) * H + 124) / 125;
    int sx = (ox * W) / 125, ex = ((ox + 1) * W + 124) / 125;
    const float* src = roiX + ((sb * 3 + j) * 252 + y1) * 252 + x1;
    float mx = -INFINITY;
    for (int r = sy; r < ey; r++)
        for (int c2 = sx; c2 < ex; c2++)
            mx = fmaxf(mx, src[r * 252 + c2]);
    h1[((bi * NCH + 20 + cc) * 125 + oy) * 125 + ox] = mx;
}

// fused conv3(5x5,35ch) + bias + BN + ReLU + 2x2s2 maxpool:
// h1[2,35,125,125] -> p3[2,50,60,60]
__global__ void conv3_pool(const float* __restrict__ h1, const float* __restrict__ w,
                           const float* __restrict__ b, const float* __restrict__ g,
                           const float* __restrict__ be, const float* __restrict__ m,
                           const float* __restrict__ v, float* __restrict__ out) {
    int px = blockIdx.x * 16 + threadIdx.x;
    int py = blockIdx.y * 16 + threadIdx.y;
    int co = blockIdx.z % 50;
    int bi = blockIdx.z / 50;
    if (px >= 60 || py >= 60) return;
    const float* wp = w + co * NCH * 25;
    const float* ip = h1 + (size_t)bi * NCH * 125 * 125;
    int iy = 2 * py, ix = 2 * px;
    float a00 = 0.f, a01 = 0.f, a10 = 0.f, a11 = 0.f;
    for (int ci = 0; ci < NCH; ci++) {
        const float* s = ip + ci * 125 * 125 + iy * 125 + ix;
        const float* wk = wp + ci * 25;
#pragma unroll
        for (int ky = 0; ky < 5; ky++) {
#pragma unroll
            for (int kx = 0; kx < 5; kx++) {
                float wv = wk[ky * 5 + kx];
                a00 += s[ky * 125 + kx] * wv;
                a01 += s[ky * 125 + kx + 1] * wv;
                a10 += s[(ky + 1) * 125 + kx] * wv;
                a11 += s[(ky + 1) * 125 + kx + 1] * wv;
            }
        }
    }
    float bb = b[co], gg = g[co], bee = be[co], mm = m[co], vv = v[co];
    a00 = fmaxf(bn_apply(a00 + bb, gg, bee, mm, vv), 0.f);
    a01 = fmaxf(bn_apply(a01 + bb, gg, bee, mm, vv), 0.f);
    a10 = fmaxf(bn_apply(a10 + bb, gg, bee, mm, vv), 0.f);
    a11 = fmaxf(bn_apply(a11 + bb, gg, bee, mm, vv), 0.f);
    float mx = fmaxf(fmaxf(a00, a01), fmaxf(a10, a11));
    out[((bi * 50 + co) * 60 + py) * 60 + px] = mx;
}

// fused conv4(5x5,50ch) + bias + BN + ReLU + 2x2s2 maxpool:
// p3[2,50,60,60] -> p4[2,25,28,28]
__global__ void conv4_pool(const float* __restrict__ p3, const float* __restrict__ w,
                           const float* __restrict__ b, const float* __restrict__ g,
                           const float* __restrict__ be, const float* __restrict__ m,
                           const float* __restrict__ v, float* __restrict__ out) {
    int px = blockIdx.x * 16 + threadIdx.x;
    int py = blockIdx.y * 16 + threadIdx.y;
    int co = blockIdx.z % 25;
    int bi = blockIdx.z / 25;
    if (px >= 28 || py >= 28) return;
    const float* wp = w + co * 50 * 25;
    const float* ip = p3 + (size_t)bi * 50 * 60 * 60;
    int iy = 2 * py, ix = 2 * px;
    float a00 = 0.f, a01 = 0.f, a10 = 0.f, a11 = 0.f;
    for (int ci = 0; ci < 50; ci++) {
        const float* s = ip + ci * 60 * 60 + iy * 60 + ix;
        const float* wk = wp + ci * 25;
#pragma unroll
        for (int ky = 0; ky < 5; ky++) {
#pragma unroll
            for (int kx = 0; kx < 5; kx++) {
                float wv = wk[ky * 5 + kx];
                a00 += s[ky * 60 + kx] * wv;
                a01 += s[ky * 60 + kx + 1] * wv;
                a10 += s[(ky + 1) * 60 + kx] * wv;
                a11 += s[(ky + 1) * 60 + kx + 1] * wv;
            }
        }
    }
    float bb = b[co], gg = g[co], bee = be[co], mm = m[co], vv = v[co];
    a00 = fmaxf(bn_apply(a00 + bb, gg, bee, mm, vv), 0.f);
    a01 = fmaxf(bn_apply(a01 + bb, gg, bee, mm, vv), 0.f);
    a10 = fmaxf(bn_apply(a10 + bb, gg, bee, mm, vv), 0.f);
    a11 = fmaxf(bn_apply(a11 + bb, gg, bee, mm, vv), 0.f);
    float mx = fmaxf(fmaxf(a00, a01), fmaxf(a10, a11));
    out[((bi * 25 + co) * 28 + py) * 28 + px] = mx;
}

// init fc1 accumulator with bias
__global__ void fc1_init(const float* __restrict__ fb1, float* __restrict__ o) {
    int idx = blockIdx.x * blockDim.x + threadIdx.x;
    if (idx < 2048) o[idx] = fb1[idx & 1023];
}

#define CHUNK 200
// fc1: [2,19600] @ [19600,1024]; grid (4 o-tiles, 98 chunks); atomic partial sums.
__global__ void fc1_mm(const float* __restrict__ h, const float* __restrict__ w,
                       float* __restrict__ out) {
    __shared__ float sh[2][CHUNK];
    int o = blockIdx.x * 256 + threadIdx.x;
    int i0 = blockIdx.y * CHUNK;
    for (int t = threadIdx.x; t < CHUNK; t += 256) {
        sh[0][t] = h[i0 + t];
        sh[1][t] = h[19600 + i0 + t];
    }
    __syncthreads();
    float a0 = 0.f, a1 = 0.f;
    const float* wp = w + (size_t)i0 * 1024 + o;
#pragma unroll 4
    for (int i = 0; i < CHUNK; i++) {
        float wv = wp[(size_t)i * 1024];
        a0 += sh[0][i] * wv;
        a1 += sh[1][i] * wv;
    }
    atomicAdd(&out[o], a0);
    atomicAdd(&out[1024 + o], a1);
}

// head: relu(fc1) -> fc2+relu -> fc3+relu -> softmax. One block per batch.
__global__ void head(const float* __restrict__ fc1o, const float* __restrict__ fw2,
                     const float* __restrict__ fb2, const float* __restrict__ fw3,
                     const float* __restrict__ fb3, float* __restrict__ out) {
    int bi = blockIdx.x;
    __shared__ float h[1024];
    __shared__ float red[256];
    __shared__ float s2[32];
    for (int i = threadIdx.x; i < 1024; i += 256) h[i] = fmaxf(fc1o[bi * 1024 + i], 0.f);
    __syncthreads();
    int o = threadIdx.x >> 3;     // 0..31
    int part = threadIdx.x & 7;   // 0..7
    float a = 0.f;
    for (int i = part * 128; i < part * 128 + 128; i++) a += h[i] * fw2[i * 32 + o];
    red[threadIdx.x] = a;
    __syncthreads();
    if (part == 0) {
        float s = 0.f;
        for (int p = 0; p < 8; p++) s += red[(o << 3) + p];
        s2[o] = fmaxf(s + fb2[o], 0.f);
    }
    __syncthreads();
    if (threadIdx.x == 0) {
        float z0 = fb3[0], z1 = fb3[1];
        for (int i = 0; i < 32; i++) {
            z0 += s2[i] * fw3[i * 2];
            z1 += s2[i] * fw3[i * 2 + 1];
        }
        z0 = fmaxf(z0, 0.f);
        z1 = fmaxf(z1, 0.f);
        float mx = fmaxf(z0, z1);
        float e0 = expf(z0 - mx), e1 = expf(z1 - mx);
        float s = e0 + e1;
        out[bi * 2 + 0] = e0 / s;
        out[bi * 2 + 1] = e1 / s;
    }
}

extern "C" void kernel_launch(void* const* d_in, const int* in_sizes, int n_in,
                              void* d_out, int out_size, void* d_ws, size_t ws_size,
                              hipStream_t stream) {
    const float* x   = (const float*)d_in[0];
    const int*   ROI = (const int*)d_in[1];
    const float* w1 = (const float*)d_in[3];
    const float* b1 = (const float*)d_in[4];
    const float* g1 = (const float*)d_in[5];
    const float* be1 = (const float*)d_in[6];
    const float* m1 = (const float*)d_in[7];
    const float* v1 = (const float*)d_in[8];
    const float* w2 = (const float*)d_in[9];
    const float* b2 = (const float*)d_in[10];
    const float* g2 = (const float*)d_in[11];
    const float* be2 = (const float*)d_in[12];
    const float* m2 = (const float*)d_in[13];
    const float* v2 = (const float*)d_in[14];
    const float* w3 = (const float*)d_in[15];
    const float* b3 = (const float*)d_in[16];
    const float* g3 = (const float*)d_in[17];
    const float* be3 = (const float*)d_in[18];
    const float* m3 = (const float*)d_in[19];
    const float* v3 = (const float*)d_in[20];
    const float* w4 = (const float*)d_in[21];
    const float* b4 = (const float*)d_in[22];
    const float* g4 = (const float*)d_in[23];
    const float* be4 = (const float*)d_in[24];
    const float* m4 = (const float*)d_in[25];
    const float* v4 = (const float*)d_in[26];
    const float* fw1 = (const float*)d_in[27];
    const float* fb1 = (const float*)d_in[28];
    const float* fw2 = (const float*)d_in[29];
    const float* fb2 = (const float*)d_in[30];
    const float* fw3 = (const float*)d_in[31];
    const float* fb3 = (const float*)d_in[32];
    float* out = (float*)d_out;

    // workspace layout (floats)
    float* ws = (float*)d_ws;
    float* roiX = ws;                         // 2*3*252*252   = 381024
    float* tmp2 = roiX + 381024;              // 2*20*252*252  = 2540160
    float* h1   = tmp2 + 2540160;             // 2*35*125*125  = 1093750
    float* p3   = h1 + 1093750;               // 2*50*60*60    = 360000
    float* p4   = p3 + 360000;                // 2*25*28*28    = 39200
    float* fc1o = p4 + 39200;                 // 2048

    // conv1 -> roiX
    {
        int total = 2 * 3 * 252 * 252;
        conv5_c1_bnrelu<<<(total + 255) / 256, 256, 0, stream>>>(x, w1, b1, g1, be1, m1, v1, roiX, 3);
    }
    // conv2 -> tmp2
    {
        int total = 2 * 20 * 252 * 252;
        conv5_c1_bnrelu<<<(total + 255) / 256, 256, 0, stream>>>(x, w2, b2, g2, be2, m2, v2, tmp2, 20);
    }
    // pool4 -> h1[:, 0:20]
    {
        int total = 2 * 20 * 125 * 125;
        pool4s2<<<(total + 255) / 256, 256, 0, stream>>>(tmp2, h1);
    }
    // roipool -> h1[:, 20:35]
    {
        int total = 2 * 15 * 125 * 125;
        roipool<<<(total + 255) / 256, 256, 0, stream>>>(roiX, ROI, h1);
    }
    // conv3 + pool -> p3
    {
        dim3 blk(16, 16);
        dim3 grd(4, 4, 2 * 50);
        conv3_pool<<<grd, blk, 0, stream>>>(h1, w3, b3, g3, be3, m3, v3, p3);
    }
    // conv4 + pool -> p4
    {
        dim3 blk(16, 16);
        dim3 grd(2, 2, 2 * 25);
        conv4_pool<<<grd, blk, 0, stream>>>(p3, w4, b4, g4, be4, m4, v4, p4);
    }
    // fc1
    fc1_init<<<8, 256, 0, stream>>>(fb1, fc1o);
    {
        dim3 grd(4, 98);
        fc1_mm<<<grd, 256, 0, stream>>>(p4, fw1, fc1o);
    }
    // head
    head<<<2, 256, 0, stream>>>(fc1o, fw2, fb2, fw3, fb3, out);
}

// Round 2
// 284.729 us; speedup vs baseline: 1.0407x; 1.0407x over previous
//
#include <hip/hip_runtime.h>
#include <math.h>

// SSNet forward. Input order (setup_inputs):
// 0 x[2,1,256,256] f32, 1 ROI[2,5,1,4] i32, 2 roi_layer (scalar=3),
// 3..8  w1[3,1,5,5] b1 g1 be1 m1 v1
// 9..14 w2[20,1,5,5] b2 g2 be2 m2 v2
// 15..20 w3[50,35,5,5] b3 g3 be3 m3 v3
// 21..26 w4[25,50,5,5] b4 g4 be4 m4 v4
// 27 fw1[19600,1024] 28 fb1[1024] 29 fw2[1024,32] 30 fb2[32] 31 fw3[32,2] 32 fb3[2]
// Output: softmax [2,2] f32.
// roi_layer is fixed at 3 by setup_inputs; grid shapes depend on it -> hard-coded RL=3.

#define RL 3
#define NCH 35   // 20 + 5*RL

__device__ __forceinline__ float bn_apply(float x, float g, float be, float m, float v) {
    float inv = g * rsqrtf(v + 1e-5f);
    return x * inv + (be - m * inv);
}

// conv 5x5, 1 input channel, on 256x256 -> [B,C,252,252], + bias + BN + ReLU
__global__ void conv5_c1_bnrelu(const float* __restrict__ x, const float* __restrict__ w,
                                const float* __restrict__ b, const float* __restrict__ g,
                                const float* __restrict__ be, const float* __restrict__ m,
                                const float* __restrict__ v, float* __restrict__ out, int C) {
    int idx = blockIdx.x * blockDim.x + threadIdx.x;
    int total = 2 * C * 252 * 252;
    if (idx >= total) return;
    int ox = idx % 252;
    int t = idx / 252;
    int oy = t % 252; t /= 252;
    int c = t % C;
    int bi = t / C;
    const float* xp = x + bi * 256 * 256 + oy * 256 + ox;
    const float* wp = w + c * 25;
    float acc = 0.f;
#pragma unroll
    for (int ky = 0; ky < 5; ky++)
#pragma unroll
        for (int kx = 0; kx < 5; kx++)
            acc += xp[ky * 256 + kx] * wp[ky * 5 + kx];
    acc += b[c];
    acc = bn_apply(acc, g[c], be[c], m[c], v[c]);
    out[idx] = fmaxf(acc, 0.f);
}

// 4x4 stride-2 max pool of [2,20,252,252] -> channels 0..19 of h1 [2,35,125,125]
__global__ void pool4s2(const float* __restrict__ in, float* __restrict__ h1) {
    int idx = blockIdx.x * blockDim.x + threadIdx.x;
    int total = 2 * 20 * 125 * 125;
    if (idx >= total) return;
    int ox = idx % 125;
    int t = idx / 125;
    int oy = t % 125; t /= 125;
    int c = t % 20;
    int bi = t / 20;
    const float* ip = in + ((bi * 20 + c) * 252 + oy * 2) * 252 + ox * 2;
    float mx = -INFINITY;
#pragma unroll
    for (int ky = 0; ky < 4; ky++)
#pragma unroll
        for (int kx = 0; kx < 4; kx++)
            mx = fmaxf(mx, ip[ky * 252 + kx]);
    h1[((bi * NCH + c) * 125 + oy) * 125 + ox] = mx;
}

// ROI adaptive max pool: roiX[2,3,252,252] -> channels 20..34 of h1.
// Batch order REVERSED (crops[1] + crops[0]): out batch b reads source batch 1-b.
// coord scale: int(v*0.9) == (9*v)/10 for v>=0.
__global__ void roipool(const float* __restrict__ roiX, const int* __restrict__ ROI,
                        float* __restrict__ h1) {
    int idx = blockIdx.x * blockDim.x + threadIdx.x;
    int total = 2 * (5 * RL) * 125 * 125;
    if (idx >= total) return;
    int ox = idx % 125;
    int t = idx / 125;
    int oy = t % 125; t /= 125;
    int cc = t % (5 * RL);
    int bi = t / (5 * RL);
    int sb = 1 - bi;
    int j = cc / 5;   // channel of roiX
    int i = cc % 5;   // roi index
    const int* rp = ROI + (sb * 5 + i) * 4;  // (y1,y2,x1,x2)
    int y1 = (9 * rp[0]) / 10;
    int y2 = (9 * rp[1]) / 10;
    int x1 = (9 * rp[2]) / 10;
    int x2 = (9 * rp[3]) / 10;
    int H = y2 - y1;
    int W = x2 - x1;
    // PyTorch adaptive bins: s = floor(o*n/125), e = ceil((o+1)*n/125)
    int sy = (oy * H) / 125, ey = ((oy + 1) * H + 124) / 125;
    int sx = (ox * W) / 125, ex = ((ox + 1) * W + 124) / 125;
    const float* src = roiX + ((sb * 3 + j) * 252 + y1) * 252 + x1;
    float mx = -INFINITY;
    for (int r = sy; r < ey; r++)
        for (int c2 = sx; c2 < ex; c2++)
            mx = fmaxf(mx, src[r * 252 + c2]);
    h1[((bi * NCH + 20 + cc) * 125 + oy) * 125 + ox] = mx;
}

// Fused conv(5x5, CI input channels) + bias + BN + ReLU + 2x2s2 maxpool,
// LDS-staged input tiles, double-buffered.
// IW: input H=W. PO: pooled output H=W. Block 16x16 threads = 16x16 pool
// outputs = 32x32 conv region = 36x36 input patch per channel.
// Weight/BN addresses are wave-uniform (co from blockIdx.z) -> s_loads via K$.
template <int IW, int PO>
__global__ __launch_bounds__(256) void conv_pool_lds(
    const float* __restrict__ in, const float* __restrict__ w,
    const float* __restrict__ b, const float* __restrict__ g,
    const float* __restrict__ be, const float* __restrict__ m,
    const float* __restrict__ v, float* __restrict__ out, int CI, int CO) {
    __shared__ float tile[2][36][38];  // 38-stride keeps float2 alignment, ~11 KB

    const int tx = threadIdx.x, ty = threadIdx.y;
    const int tid = ty * 16 + tx;
    const int zz = blockIdx.z;
    const int co = zz % CO;
    const int bi = zz / CO;
    const int px = blockIdx.x * 16 + tx;
    const int py = blockIdx.y * 16 + ty;
    const bool valid = (px < PO) && (py < PO);
    const int iy0 = blockIdx.y * 32;
    const int ix0 = blockIdx.x * 32;
    const float* ip = in + (size_t)bi * CI * IW * IW;
    const float* wp = w + (size_t)co * CI * 25;

    // stage channel ci into buffer buf
    auto stage = [&](int buf, int ci) {
        const float* src = ip + (size_t)ci * IW * IW;
        for (int i = tid; i < 36 * 36; i += 256) {
            int r = i / 36;
            int c = i - r * 36;
            int gy = iy0 + r, gx = ix0 + c;
            float val = (gy < IW && gx < IW) ? src[gy * IW + gx] : 0.f;
            tile[buf][r][c] = val;
        }
    };

    float a00 = 0.f, a01 = 0.f, a10 = 0.f, a11 = 0.f;
    stage(0, 0);
    for (int ci = 0; ci < CI; ci++) {
        __syncthreads();               // buf[ci&1] staged; prev reads done
        if (ci + 1 < CI) stage((ci + 1) & 1, ci + 1);
        // read the 6x6 patch as float2 (8B-aligned: 2*tx+2*c even)
        float2 p[6][3];
#pragma unroll
        for (int r = 0; r < 6; r++)
#pragma unroll
            for (int c = 0; c < 3; c++)
                p[r][c] = *(const float2*)&tile[ci & 1][2 * ty + r][2 * tx + 2 * c];
        const float* wk = wp + ci * 25;
#define E(r, cc) (((cc) & 1) ? p[r][(cc) >> 1].y : p[r][(cc) >> 1].x)
#pragma unroll
        for (int ky = 0; ky < 5; ky++) {
#pragma unroll
            for (int kx = 0; kx < 5; kx++) {
                float wv = wk[ky * 5 + kx];
                a00 = fmaf(E(ky, kx), wv, a00);
                a01 = fmaf(E(ky, kx + 1), wv, a01);
                a10 = fmaf(E(ky + 1, kx), wv, a10);
                a11 = fmaf(E(ky + 1, kx + 1), wv, a11);
            }
        }
#undef E
    }
    if (valid) {
        // bn(acc + b) = acc*inv + ((b - m)*inv + be)
        float inv = g[co] * rsqrtf(v[co] + 1e-5f);
        float sh = (b[co] - m[co]) * inv + be[co];
        a00 = fmaxf(a00 * inv + sh, 0.f);
        a01 = fmaxf(a01 * inv + sh, 0.f);
        a10 = fmaxf(a10 * inv + sh, 0.f);
        a11 = fmaxf(a11 * inv + sh, 0.f);
        float mx = fmaxf(fmaxf(a00, a01), fmaxf(a10, a11));
        out[(((size_t)bi * CO + co) * PO + py) * PO + px] = mx;
    }
}

// init fc1 accumulator with bias
__global__ void fc1_init(const float* __restrict__ fb1, float* __restrict__ o) {
    int idx = blockIdx.x * blockDim.x + threadIdx.x;
    if (idx < 2048) o[idx] = fb1[idx & 1023];
}

#define CHUNK 200
// fc1: [2,19600] @ [19600,1024]; grid (4 o-tiles, 98 chunks); atomic partial sums.
__global__ void fc1_mm(const float* __restrict__ h, const float* __restrict__ w,
                       float* __restrict__ out) {
    __shared__ float sh[2][CHUNK];
    int o = blockIdx.x * 256 + threadIdx.x;
    int i0 = blockIdx.y * CHUNK;
    for (int t = threadIdx.x; t < CHUNK; t += 256) {
        sh[0][t] = h[i0 + t];
        sh[1][t] = h[19600 + i0 + t];
    }
    __syncthreads();
    float a0 = 0.f, a1 = 0.f;
    const float* wp = w + (size_t)i0 * 1024 + o;
#pragma unroll 4
    for (int i = 0; i < CHUNK; i++) {
        float wv = wp[(size_t)i * 1024];
        a0 += sh[0][i] * wv;
        a1 += sh[1][i] * wv;
    }
    atomicAdd(&out[o], a0);
    atomicAdd(&out[1024 + o], a1);
}

// head: relu(fc1) -> fc2+relu -> fc3+relu -> softmax. One block per batch.
__global__ void head(const float* __restrict__ fc1o, const float* __restrict__ fw2,
                     const float* __restrict__ fb2, const float* __restrict__ fw3,
                     const float* __restrict__ fb3, float* __restrict__ out) {
    int bi = blockIdx.x;
    __shared__ float h[1024];
    __shared__ float red[256];
    __shared__ float s2[32];
    for (int i = threadIdx.x; i < 1024; i += 256) h[i] = fmaxf(fc1o[bi * 1024 + i], 0.f);
    __syncthreads();
    int o = threadIdx.x >> 3;     // 0..31
    int part = threadIdx.x & 7;   // 0..7
    float a = 0.f;
    for (int i = part * 128; i < part * 128 + 128; i++) a += h[i] * fw2[i * 32 + o];
    red[threadIdx.x] = a;
    __syncthreads();
    if (part == 0) {
        float s = 0.f;
        for (int p = 0; p < 8; p++) s += red[(o << 3) + p];
        s2[o] = fmaxf(s + fb2[o], 0.f);
    }
    __syncthreads();
    if (threadIdx.x == 0) {
        float z0 = fb3[0], z1 = fb3[1];
        for (int i = 0; i < 32; i++) {
            z0 += s2[i] * fw3[i * 2];
            z1 += s2[i] * fw3[i * 2 + 1];
        }
        z0 = fmaxf(z0, 0.f);
        z1 = fmaxf(z1, 0.f);
        float mx = fmaxf(z0, z1);
        float e0 = expf(z0 - mx), e1 = expf(z1 - mx);
        float s = e0 + e1;
        out[bi * 2 + 0] = e0 / s;
        out[bi * 2 + 1] = e1 / s;
    }
}

extern "C" void kernel_launch(void* const* d_in, const int* in_sizes, int n_in,
                              void* d_out, int out_size, void* d_ws, size_t ws_size,
                              hipStream_t stream) {
    const float* x   = (const float*)d_in[0];
    const int*   ROI = (const int*)d_in[1];
    const float* w1 = (const float*)d_in[3];
    const float* b1 = (const float*)d_in[4];
    const float* g1 = (const float*)d_in[5];
    const float* be1 = (const float*)d_in[6];
    const float* m1 = (const float*)d_in[7];
    const float* v1 = (const float*)d_in[8];
    const float* w2 = (const float*)d_in[9];
    const float* b2 = (const float*)d_in[10];
    const float* g2 = (const float*)d_in[11];
    const float* be2 = (const float*)d_in[12];
    const float* m2 = (const float*)d_in[13];
    const float* v2 = (const float*)d_in[14];
    const float* w3 = (const float*)d_in[15];
    const float* b3 = (const float*)d_in[16];
    const float* g3 = (const float*)d_in[17];
    const float* be3 = (const float*)d_in[18];
    const float* m3 = (const float*)d_in[19];
    const float* v3 = (const float*)d_in[20];
    const float* w4 = (const float*)d_in[21];
    const float* b4 = (const float*)d_in[22];
    const float* g4 = (const float*)d_in[23];
    const float* be4 = (const float*)d_in[24];
    const float* m4 = (const float*)d_in[25];
    const float* v4 = (const float*)d_in[26];
    const float* fw1 = (const float*)d_in[27];
    const float* fb1 = (const float*)d_in[28];
    const float* fw2 = (const float*)d_in[29];
    const float* fb2 = (const float*)d_in[30];
    const float* fw3 = (const float*)d_in[31];
    const float* fb3 = (const float*)d_in[32];
    float* out = (float*)d_out;

    // workspace layout (floats)
    float* ws = (float*)d_ws;
    float* roiX = ws;                         // 2*3*252*252   = 381024
    float* tmp2 = roiX + 381024;              // 2*20*252*252  = 2540160
    float* h1   = tmp2 + 2540160;             // 2*35*125*125  = 1093750
    float* p3   = h1 + 1093750;               // 2*50*60*60    = 360000
    float* p4   = p3 + 360000;                // 2*25*28*28    = 39200
    float* fc1o = p4 + 39200;                 // 2048

    // conv1 -> roiX
    {
        int total = 2 * 3 * 252 * 252;
        conv5_c1_bnrelu<<<(total + 255) / 256, 256, 0, stream>>>(x, w1, b1, g1, be1, m1, v1, roiX, 3);
    }
    // conv2 -> tmp2
    {
        int total = 2 * 20 * 252 * 252;
        conv5_c1_bnrelu<<<(total + 255) / 256, 256, 0, stream>>>(x, w2, b2, g2, be2, m2, v2, tmp2, 20);
    }
    // pool4 -> h1[:, 0:20]
    {
        int total = 2 * 20 * 125 * 125;
        pool4s2<<<(total + 255) / 256, 256, 0, stream>>>(tmp2, h1);
    }
    // roipool -> h1[:, 20:35]
    {
        int total = 2 * 15 * 125 * 125;
        roipool<<<(total + 255) / 256, 256, 0, stream>>>(roiX, ROI, h1);
    }
    // conv3 + pool -> p3  (LDS-staged)
    {
        dim3 blk(16, 16);
        dim3 grd(4, 4, 2 * 50);
        conv_pool_lds<125, 60><<<grd, blk, 0, stream>>>(h1, w3, b3, g3, be3, m3, v3, p3, NCH, 50);
    }
    // conv4 + pool -> p4  (LDS-staged)
    {
        dim3 blk(16, 16);
        dim3 grd(2, 2, 2 * 25);
        conv_pool_lds<60, 28><<<grd, blk, 0, stream>>>(p3, w4, b4, g4, be4, m4, v4, p4, 50, 25);
    }
    // fc1
    fc1_init<<<8, 256, 0, stream>>>(fb1, fc1o);
    {
        dim3 grd(4, 98);
        fc1_mm<<<grd, 256, 0, stream>>>(p4, fw1, fc1o);
    }
    // head
    head<<<2, 256, 0, stream>>>(fc1o, fw2, fb2, fw3, fb3, out);
}

// Round 3
// 232.329 us; speedup vs baseline: 1.2755x; 1.2255x over previous
//
#include <hip/hip_runtime.h>
#include <math.h>

// SSNet forward. Input order (setup_inputs):
// 0 x[2,1,256,256] f32, 1 ROI[2,5,1,4] i32, 2 roi_layer (scalar=3),
// 3..8  w1[3,1,5,5] b1 g1 be1 m1 v1
// 9..14 w2[20,1,5,5] b2 g2 be2 m2 v2
// 15..20 w3[50,35,5,5] b3 g3 be3 m3 v3
// 21..26 w4[25,50,5,5] b4 g4 be4 m4 v4
// 27 fw1[19600,1024] 28 fb1[1024] 29 fw2[1024,32] 30 fb2[32] 31 fw3[32,2] 32 fb3[2]
// Output: softmax [2,2] f32.
// roi_layer fixed at 3 by setup_inputs -> hard-coded RL=3.

#define RL 3
#define NCH 35   // 20 + 5*RL

__device__ __forceinline__ float bn_apply(float x, float g, float be, float m, float v) {
    float inv = g * rsqrtf(v + 1e-5f);
    return x * inv + (be - m * inv);
}

// conv 5x5, 1 input channel, on 256x256 -> [B,C,252,252], + bias + BN + ReLU
__global__ void conv5_c1_bnrelu(const float* __restrict__ x, const float* __restrict__ w,
                                const float* __restrict__ b, const float* __restrict__ g,
                                const float* __restrict__ be, const float* __restrict__ m,
                                const float* __restrict__ v, float* __restrict__ out, int C) {
    int idx = blockIdx.x * blockDim.x + threadIdx.x;
    int total = 2 * C * 252 * 252;
    if (idx >= total) return;
    int ox = idx % 252;
    int t = idx / 252;
    int oy = t % 252; t /= 252;
    int c = t % C;
    int bi = t / C;
    const float* xp = x + bi * 256 * 256 + oy * 256 + ox;
    const float* wp = w + c * 25;
    float acc = 0.f;
#pragma unroll
    for (int ky = 0; ky < 5; ky++)
#pragma unroll
        for (int kx = 0; kx < 5; kx++)
            acc = fmaf(xp[ky * 256 + kx], wp[ky * 5 + kx], acc);
    acc += b[c];
    acc = bn_apply(acc, g[c], be[c], m[c], v[c]);
    out[idx] = fmaxf(acc, 0.f);
}

// Fused conv2(5x5,1ch)+bias+BN+ReLU+4x4s2 maxpool: x[2,1,256,256] -> h1 ch 0..19.
// blockIdx.y encodes (bi,c) -> c wave-uniform -> scalar weight loads.
// Index math: pooled (oy,ox) needs conv rows 2oy..2oy+3 -> input rows 2oy..2oy+7; max 255, no bounds.
__global__ __launch_bounds__(256) void conv2_pool(const float* __restrict__ x,
                                                  const float* __restrict__ w,
                                                  const float* __restrict__ b, const float* __restrict__ g,
                                                  const float* __restrict__ be, const float* __restrict__ m,
                                                  const float* __restrict__ v, float* __restrict__ h1) {
    int c = blockIdx.y % 20;
    int bi = blockIdx.y / 20;
    int i = blockIdx.x * 256 + threadIdx.x;
    if (i >= 125 * 125) return;
    int oy = i / 125, ox = i % 125;
    const float* xp = x + bi * 256 * 256 + (2 * oy) * 256 + 2 * ox;
    float wl[25];
#pragma unroll
    for (int k = 0; k < 25; k++) wl[k] = w[c * 25 + k];
    float in[8][8];
#pragma unroll
    for (int r = 0; r < 8; r++)
#pragma unroll
        for (int cc = 0; cc < 8; cc++) in[r][cc] = xp[r * 256 + cc];
    float inv = g[c] * rsqrtf(v[c] + 1e-5f);
    float sh = (b[c] - m[c]) * inv + be[c];
    float mx = -INFINITY;
#pragma unroll
    for (int py = 0; py < 4; py++) {
#pragma unroll
        for (int px = 0; px < 4; px++) {
            float acc = 0.f;
#pragma unroll
            for (int ky = 0; ky < 5; ky++)
#pragma unroll
                for (int kx = 0; kx < 5; kx++)
                    acc = fmaf(in[py + ky][px + kx], wl[ky * 5 + kx], acc);
            mx = fmaxf(mx, fmaxf(acc * inv + sh, 0.f));
        }
    }
    h1[((bi * NCH + c) * 125 + oy) * 125 + ox] = mx;
}

// ROI adaptive max pool: roiX[2,3,252,252] -> channels 20..34 of h1.
// Batch order REVERSED (crops[1] + crops[0]): out batch b reads source batch 1-b.
// coord scale: int(v*0.9) == (9*v)/10 for v>=0.
__global__ void roipool(const float* __restrict__ roiX, const int* __restrict__ ROI,
                        float* __restrict__ h1) {
    int idx = blockIdx.x * blockDim.x + threadIdx.x;
    int total = 2 * (5 * RL) * 125 * 125;
    if (idx >= total) return;
    int ox = idx % 125;
    int t = idx / 125;
    int oy = t % 125; t /= 125;
    int cc = t % (5 * RL);
    int bi = t / (5 * RL);
    int sb = 1 - bi;
    int j = cc / 5;   // channel of roiX
    int i = cc % 5;   // roi index
    const int* rp = ROI + (sb * 5 + i) * 4;  // (y1,y2,x1,x2)
    int y1 = (9 * rp[0]) / 10;
    int y2 = (9 * rp[1]) / 10;
    int x1 = (9 * rp[2]) / 10;
    int x2 = (9 * rp[3]) / 10;
    int H = y2 - y1;
    int W = x2 - x1;
    // PyTorch adaptive bins: s = floor(o*n/125), e = ceil((o+1)*n/125)
    int sy = (oy * H) / 125, ey = ((oy + 1) * H + 124) / 125;
    int sx = (ox * W) / 125, ex = ((ox + 1) * W + 124) / 125;
    const float* src = roiX + ((sb * 3 + j) * 252 + y1) * 252 + x1;
    float mx = -INFINITY;
    for (int r = sy; r < ey; r++)
        for (int c2 = sx; c2 < ex; c2++)
            mx = fmaxf(mx, src[r * 252 + c2]);
    h1[((bi * NCH + 20 + cc) * 125 + oy) * 125 + ox] = mx;
}

// conv3: fused conv(5x5, CI ch) + bias+BN+ReLU + 2x2s2 pool, LDS-staged,
// G output channels per block (staging amortized Gx).
// Block 16x16 threads = 16x16 pool outputs. Grid (ceil(PO/16), ceil(PO/16), 2*CO/G).
template <int IW, int PO, int CI, int CO, int G>
__global__ __launch_bounds__(256) void conv_pool_g(
    const float* __restrict__ in, const float* __restrict__ w,
    const float* __restrict__ b, const float* __restrict__ g,
    const float* __restrict__ be, const float* __restrict__ m,
    const float* __restrict__ v, float* __restrict__ out) {
    __shared__ float tile[2][36][38];  // float2-aligned stride, ~11 KB

    const int tx = threadIdx.x, ty = threadIdx.y;
    const int tid = ty * 16 + tx;
    const int co0 = (blockIdx.z % (CO / G)) * G;
    const int bi = blockIdx.z / (CO / G);
    const int px = blockIdx.x * 16 + tx;
    const int py = blockIdx.y * 16 + ty;
    const bool valid = (px < PO) && (py < PO);
    const int iy0 = blockIdx.y * 32;
    const int ix0 = blockIdx.x * 32;
    const float* ip = in + (size_t)bi * CI * IW * IW;

    auto stage = [&](int buf, int ci) {
        const float* src = ip + (size_t)ci * IW * IW;
        for (int i = tid; i < 36 * 36; i += 256) {
            int r = i / 36;
            int c = i - r * 36;
            int gy = iy0 + r, gx = ix0 + c;
            tile[buf][r][c] = (gy < IW && gx < IW) ? src[gy * IW + gx] : 0.f;
        }
    };

    float acc[G][4];
#pragma unroll
    for (int gg = 0; gg < G; gg++)
#pragma unroll
        for (int q = 0; q < 4; q++) acc[gg][q] = 0.f;

    stage(0, 0);
    for (int ci = 0; ci < CI; ci++) {
        __syncthreads();
        if (ci + 1 < CI) stage((ci + 1) & 1, ci + 1);
        float2 p[6][3];
#pragma unroll
        for (int r = 0; r < 6; r++)
#pragma unroll
            for (int c = 0; c < 3; c++)
                p[r][c] = *(const float2*)&tile[ci & 1][2 * ty + r][2 * tx + 2 * c];
#define E(r, cc) (((cc) & 1) ? p[r][(cc) >> 1].y : p[r][(cc) >> 1].x)
#pragma unroll
        for (int gg = 0; gg < G; gg++) {
            const float* wk = w + ((size_t)(co0 + gg) * CI + ci) * 25;
#pragma unroll
            for (int ky = 0; ky < 5; ky++) {
#pragma unroll
                for (int kx = 0; kx < 5; kx++) {
                    float wv = wk[ky * 5 + kx];
                    acc[gg][0] = fmaf(E(ky, kx), wv, acc[gg][0]);
                    acc[gg][1] = fmaf(E(ky, kx + 1), wv, acc[gg][1]);
                    acc[gg][2] = fmaf(E(ky + 1, kx), wv, acc[gg][2]);
                    acc[gg][3] = fmaf(E(ky + 1, kx + 1), wv, acc[gg][3]);
                }
            }
        }
#undef E
    }
    if (valid) {
#pragma unroll
        for (int gg = 0; gg < G; gg++) {
            int co = co0 + gg;
            float inv = g[co] * rsqrtf(v[co] + 1e-5f);
            float sh = (b[co] - m[co]) * inv + be[co];
            float a0 = fmaxf(acc[gg][0] * inv + sh, 0.f);
            float a1 = fmaxf(acc[gg][1] * inv + sh, 0.f);
            float a2 = fmaxf(acc[gg][2] * inv + sh, 0.f);
            float a3 = fmaxf(acc[gg][3] * inv + sh, 0.f);
            out[(((size_t)bi * CO + co) * PO + py) * PO + px] =
                fmaxf(fmaxf(a0, a1), fmaxf(a2, a3));
        }
    }
}

// conv4: block = 4 co-subgroups x (8x8 spatial pool outputs). Patch 20x20 per ci
// staged once, shared by all 4 subgroups (LDS same-address broadcast).
// Grid (4, 4, 2*7): co = (z%7)*4+sg (mask co<25), bi = z/7.
__global__ __launch_bounds__(256) void conv4_pool_sg(
    const float* __restrict__ p3, const float* __restrict__ w,
    const float* __restrict__ b, const float* __restrict__ g,
    const float* __restrict__ be, const float* __restrict__ m,
    const float* __restrict__ v, float* __restrict__ out) {
    __shared__ float tile[2][20][22];  // 3.5 KB

    const int tid = threadIdx.x;
    const int sg = tid >> 6;
    const int lane = tid & 63;
    const int sy = lane >> 3, sx = lane & 7;
    const int co = (blockIdx.z % 7) * 4 + sg;
    const int bi = blockIdx.z / 7;
    const int px = blockIdx.x * 8 + sx;
    const int py = blockIdx.y * 8 + sy;
    const bool valid = (px < 28) && (py < 28) && (co < 25);
    const int iy0 = blockIdx.y * 16;
    const int ix0 = blockIdx.x * 16;
    const float* ip = p3 + (size_t)bi * 50 * 60 * 60;

    auto stage = [&](int buf, int ci) {
        const float* src = ip + (size_t)ci * 60 * 60;
        for (int i = tid; i < 20 * 20; i += 256) {
            int r = i / 20;
            int c = i - r * 20;
            int gy = iy0 + r, gx = ix0 + c;
            tile[buf][r][c] = (gy < 60 && gx < 60) ? src[gy * 60 + gx] : 0.f;
        }
    };

    float a0 = 0.f, a1 = 0.f, a2 = 0.f, a3 = 0.f;
    stage(0, 0);
    const int cw = (co < 25) ? co : 0;
    for (int ci = 0; ci < 50; ci++) {
        __syncthreads();
        if (ci + 1 < 50) stage((ci + 1) & 1, ci + 1);
        float2 p[6][3];
#pragma unroll
        for (int r = 0; r < 6; r++)
#pragma unroll
            for (int c = 0; c < 3; c++)
                p[r][c] = *(const float2*)&tile[ci & 1][2 * sy + r][2 * sx + 2 * c];
        const float* wk = w + ((size_t)cw * 50 + ci) * 25;
#define E(r, cc) (((cc) & 1) ? p[r][(cc) >> 1].y : p[r][(cc) >> 1].x)
#pragma unroll
        for (int ky = 0; ky < 5; ky++) {
#pragma unroll
            for (int kx = 0; kx < 5; kx++) {
                float wv = wk[ky * 5 + kx];
                a0 = fmaf(E(ky, kx), wv, a0);
                a1 = fmaf(E(ky, kx + 1), wv, a1);
                a2 = fmaf(E(ky + 1, kx), wv, a2);
                a3 = fmaf(E(ky + 1, kx + 1), wv, a3);
            }
        }
#undef E
    }
    if (valid) {
        float inv = g[co] * rsqrtf(v[co] + 1e-5f);
        float sh = (b[co] - m[co]) * inv + be[co];
        a0 = fmaxf(a0 * inv + sh, 0.f);
        a1 = fmaxf(a1 * inv + sh, 0.f);
        a2 = fmaxf(a2 * inv + sh, 0.f);
        a3 = fmaxf(a3 * inv + sh, 0.f);
        out[(((size_t)bi * 25 + co) * 28 + py) * 28 + px] =
            fmaxf(fmaxf(a0, a1), fmaxf(a2, a3));
    }
}

// init fc1 accumulator with bias
__global__ void fc1_init(const float* __restrict__ fb1, float* __restrict__ o) {
    int idx = blockIdx.x * blockDim.x + threadIdx.x;
    if (idx < 2048) o[idx] = fb1[idx & 1023];
}

#define CHUNK 200
// fc1: [2,19600] @ [19600,1024]; grid (4 o-tiles, 98 chunks); atomic partial sums.
__global__ void fc1_mm(const float* __restrict__ h, const float* __restrict__ w,
                       float* __restrict__ out) {
    __shared__ float sh[2][CHUNK];
    int o = blockIdx.x * 256 + threadIdx.x;
    int i0 = blockIdx.y * CHUNK;
    for (int t = threadIdx.x; t < CHUNK; t += 256) {
        sh[0][t] = h[i0 + t];
        sh[1][t] = h[19600 + i0 + t];
    }
    __syncthreads();
    float a0 = 0.f, a1 = 0.f;
    const float* wp = w + (size_t)i0 * 1024 + o;
#pragma unroll 4
    for (int i = 0; i < CHUNK; i++) {
        float wv = wp[(size_t)i * 1024];
        a0 += sh[0][i] * wv;
        a1 += sh[1][i] * wv;
    }
    atomicAdd(&out[o], a0);
    atomicAdd(&out[1024 + o], a1);
}

// head: relu(fc1) -> fc2+relu -> fc3+relu -> softmax. One block per batch.
__global__ void head(const float* __restrict__ fc1o, const float* __restrict__ fw2,
                     const float* __restrict__ fb2, const float* __restrict__ fw3,
                     const float* __restrict__ fb3, float* __restrict__ out) {
    int bi = blockIdx.x;
    __shared__ float h[1024];
    __shared__ float red[256];
    __shared__ float s2[32];
    for (int i = threadIdx.x; i < 1024; i += 256) h[i] = fmaxf(fc1o[bi * 1024 + i], 0.f);
    __syncthreads();
    int o = threadIdx.x >> 3;     // 0..31
    int part = threadIdx.x & 7;   // 0..7
    float a = 0.f;
    for (int i = part * 128; i < part * 128 + 128; i++) a += h[i] * fw2[i * 32 + o];
    red[threadIdx.x] = a;
    __syncthreads();
    if (part == 0) {
        float s = 0.f;
        for (int p = 0; p < 8; p++) s += red[(o << 3) + p];
        s2[o] = fmaxf(s + fb2[o], 0.f);
    }
    __syncthreads();
    if (threadIdx.x == 0) {
        float z0 = fb3[0], z1 = fb3[1];
        for (int i = 0; i < 32; i++) {
            z0 += s2[i] * fw3[i * 2];
            z1 += s2[i] * fw3[i * 2 + 1];
        }
        z0 = fmaxf(z0, 0.f);
        z1 = fmaxf(z1, 0.f);
        float mx = fmaxf(z0, z1);
        float e0 = expf(z0 - mx), e1 = expf(z1 - mx);
        float s = e0 + e1;
        out[bi * 2 + 0] = e0 / s;
        out[bi * 2 + 1] = e1 / s;
    }
}

extern "C" void kernel_launch(void* const* d_in, const int* in_sizes, int n_in,
                              void* d_out, int out_size, void* d_ws, size_t ws_size,
                              hipStream_t stream) {
    const float* x   = (const float*)d_in[0];
    const int*   ROI = (const int*)d_in[1];
    const float* w1 = (const float*)d_in[3];
    const float* b1 = (const float*)d_in[4];
    const float* g1 = (const float*)d_in[5];
    const float* be1 = (const float*)d_in[6];
    const float* m1 = (const float*)d_in[7];
    const float* v1 = (const float*)d_in[8];
    const float* w2 = (const float*)d_in[9];
    const float* b2 = (const float*)d_in[10];
    const float* g2 = (const float*)d_in[11];
    const float* be2 = (const float*)d_in[12];
    const float* m2 = (const float*)d_in[13];
    const float* v2 = (const float*)d_in[14];
    const float* w3 = (const float*)d_in[15];
    const float* b3 = (const float*)d_in[16];
    const float* g3 = (const float*)d_in[17];
    const float* be3 = (const float*)d_in[18];
    const float* m3 = (const float*)d_in[19];
    const float* v3 = (const float*)d_in[20];
    const float* w4 = (const float*)d_in[21];
    const float* b4 = (const float*)d_in[22];
    const float* g4 = (const float*)d_in[23];
    const float* be4 = (const float*)d_in[24];
    const float* m4 = (const float*)d_in[25];
    const float* v4 = (const float*)d_in[26];
    const float* fw1 = (const float*)d_in[27];
    const float* fb1 = (const float*)d_in[28];
    const float* fw2 = (const float*)d_in[29];
    const float* fb2 = (const float*)d_in[30];
    const float* fw3 = (const float*)d_in[31];
    const float* fb3 = (const float*)d_in[32];
    float* out = (float*)d_out;

    // workspace layout (floats)
    float* ws = (float*)d_ws;
    float* roiX = ws;                         // 2*3*252*252   = 381024
    float* h1   = roiX + 381024;              // 2*35*125*125  = 1093750
    float* p3   = h1 + 1093750;               // 2*50*60*60    = 360000
    float* p4   = p3 + 360000;                // 2*25*28*28    = 39200
    float* fc1o = p4 + 39200;                 // 2048

    // conv1 -> roiX
    {
        int total = 2 * 3 * 252 * 252;
        conv5_c1_bnrelu<<<(total + 255) / 256, 256, 0, stream>>>(x, w1, b1, g1, be1, m1, v1, roiX, 3);
    }
    // conv2 + 4x4s2 pool -> h1[:, 0:20]   (fused)
    {
        dim3 grd((125 * 125 + 255) / 256, 40);
        conv2_pool<<<grd, 256, 0, stream>>>(x, w2, b2, g2, be2, m2, v2, h1);
    }
    // roipool -> h1[:, 20:35]
    {
        int total = 2 * 15 * 125 * 125;
        roipool<<<(total + 255) / 256, 256, 0, stream>>>(roiX, ROI, h1);
    }
    // conv3 + pool -> p3  (LDS-staged, G=5 co per block)
    {
        dim3 blk(16, 16);
        dim3 grd(4, 4, 2 * 10);
        conv_pool_g<125, 60, NCH, 50, 5><<<grd, blk, 0, stream>>>(h1, w3, b3, g3, be3, m3, v3, p3);
    }
    // conv4 + pool -> p4  (subgroup layout)
    {
        dim3 blk(256);
        dim3 grd(4, 4, 2 * 7);
        conv4_pool_sg<<<grd, blk, 0, stream>>>(p3, w4, b4, g4, be4, m4, v4, p4);
    }
    // fc1
    fc1_init<<<8, 256, 0, stream>>>(fb1, fc1o);
    {
        dim3 grd(4, 98);
        fc1_mm<<<grd, 256, 0, stream>>>(p4, fw1, fc1o);
    }
    // head
    head<<<2, 256, 0, stream>>>(fc1o, fw2, fb2, fw3, fb3, out);
}